// Round 4
// baseline (331.619 us; speedup 1.0000x reference)
//
#include <hip/hip_runtime.h>

// TriDiagonalLaplaceSolver: B=4096 independent rows, N=8192 per row.
// Thomas algorithm with precomputed LU factors a (N), b (N-1), c (N-1).
//   fwd: y[i] = x[i] - c[i-1]*y[i-1]        (y[0] = x[0])
//   bwd: z[i] = (y[i] - b[i]*z[i+1])/a[i]   (z[N-1] = y[N-1]/a[N-1])
// Both recurrences contract (ratio ~0.268/step) => HALO=16 zero-init warm-up
// reproduces exact state to ~3e-10 relative.
//
// R1-R3 lessons:
//  - float y[WIN] array = alloca; PromoteAlloca refuses under occupancy
//    heuristic -> whole window in scratch (R2: +178 MB spill writes).
//  - v80f32 single vector: not a legal reg class (max v32 tuple) -> partial
//    stack split (R3: still VGPR_Count=64, +98 MB spill writes).
//  - __launch_bounds__(256,4) is a MIN-occupancy bound (reg CAP); compiler
//    still CHOSE 8 waves/EU = 64 VGPRs and spilled.
// R4 fix: amdgpu_waves_per_eu(4,4) pins exactly 4 waves/EU -> compiler
// targets 128 VGPRs; storage = five v16f32 vectors (legal 16-reg tuples,
// constant lane indices after full unroll). Live set ~110 <= 128.

#define NN    8192
#define BB    4096
#define CHUNK 64
#define HALO  16

typedef float v16 __attribute__((ext_vector_type(16)));

// y-window accessors: k is a literal constant after full unroll -> the
// comparison chain folds and lane indices are constants.
#define YGET(k) ((k) < 16 ? y0[(k) & 15] : (k) < 32 ? y1[(k) & 15] : \
                 (k) < 48 ? y2[(k) & 15] : y3[(k) & 15])
#define YSET(k, v_) do { \
    if ((k) < 16)      y0[(k) & 15] = (v_); \
    else if ((k) < 32) y1[(k) & 15] = (v_); \
    else if ((k) < 48) y2[(k) & 15] = (v_); \
    else               y3[(k) & 15] = (v_); } while (0)

__device__ __forceinline__ float fast_rcp(float v) {
    float r = __builtin_amdgcn_rcpf(v);
    return r * (2.0f - v * r);   // one NR step -> ~0.5 ulp
}

template<bool FIRST, bool EDGE>
__device__ __forceinline__ void solve_window(
    const float* __restrict__ xrow,
    const float* __restrict__ a,
    const float* __restrict__ b,
    const float* __restrict__ c,
    float* __restrict__ orow,
    int s)
{
    const float* xs = xrow + s;
    const float* as = a + s;
    const float* bs = b + s;
    const float* cs = c + s;   // c[i-1] == cs[k-1]

    float y = 0.0f;

    if (!FIRST) {
        // forward warm-up over [s-HALO, s): contraction kills zero-init error
        const float* xw = xs - HALO;
        const float* cw = cs - HALO;
        #pragma unroll
        for (int k = 0; k < HALO; k += 4) {
            float4 xv = *(const float4*)(xw + k);
            y = xv.x - cw[k - 1] * y;
            y = xv.y - cw[k]     * y;
            y = xv.z - cw[k + 1] * y;
            y = xv.w - cw[k + 2] * y;
        }
    }

    v16 y0, y1, y2, y3, yh;

    // forward main over the chunk: y stored in register tuples
    #pragma unroll
    for (int k = 0; k < CHUNK; k += 4) {
        float4 xv = *(const float4*)(xs + k);
        float c0 = (FIRST && k == 0) ? 0.0f : cs[k - 1];
        y = xv.x - c0        * y;  YSET(k,     y);
        y = xv.y - cs[k]     * y;  YSET(k + 1, y);
        y = xv.z - cs[k + 1] * y;  YSET(k + 2, y);
        y = xv.w - cs[k + 2] * y;  YSET(k + 3, y);
    }

    float z = 0.0f;
    if (!EDGE) {
        // forward continuation into the halo [CHUNK, CHUNK+HALO)
        #pragma unroll
        for (int k = CHUNK; k < CHUNK + HALO; k += 4) {
            float4 xv = *(const float4*)(xs + k);
            y = xv.x - cs[k - 1] * y;  yh[(k - CHUNK)]     = y;
            y = xv.y - cs[k]     * y;  yh[(k - CHUNK) + 1] = y;
            y = xv.z - cs[k + 1] * y;  yh[(k - CHUNK) + 2] = y;
            y = xv.w - cs[k + 2] * y;  yh[(k - CHUNK) + 3] = y;
        }
        // backward warm-up over the halo (z state converges, values dropped)
        #pragma unroll
        for (int k = CHUNK + HALO - 1; k >= CHUNK; --k) {
            z = (yh[k - CHUNK] - bs[k] * z) * fast_rcp(as[k]);
        }
        // backward main: emit float4 stores descending
        #pragma unroll
        for (int kg = CHUNK - 4; kg >= 0; kg -= 4) {
            float4 zv;
            z = (YGET(kg + 3) - bs[kg + 3] * z) * fast_rcp(as[kg + 3]); zv.w = z;
            z = (YGET(kg + 2) - bs[kg + 2] * z) * fast_rcp(as[kg + 2]); zv.z = z;
            z = (YGET(kg + 1) - bs[kg + 1] * z) * fast_rcp(as[kg + 1]); zv.y = z;
            z = (YGET(kg)     - bs[kg]     * z) * fast_rcp(as[kg]);     zv.x = z;
            *(float4*)(orow + s + kg) = zv;
        }
    } else {
        // last chunk: z[N-1] = y[N-1]/a[N-1]  (b_pad[N-1]=0, z starts at 0)
        {
            float4 zv;
            z = YGET(CHUNK - 1) * fast_rcp(as[CHUNK - 1]);                        zv.w = z;
            z = (YGET(CHUNK - 2) - bs[CHUNK - 2] * z) * fast_rcp(as[CHUNK - 2]);  zv.z = z;
            z = (YGET(CHUNK - 3) - bs[CHUNK - 3] * z) * fast_rcp(as[CHUNK - 3]);  zv.y = z;
            z = (YGET(CHUNK - 4) - bs[CHUNK - 4] * z) * fast_rcp(as[CHUNK - 4]);  zv.x = z;
            *(float4*)(orow + s + CHUNK - 4) = zv;
        }
        #pragma unroll
        for (int kg = CHUNK - 8; kg >= 0; kg -= 4) {
            float4 zv;
            z = (YGET(kg + 3) - bs[kg + 3] * z) * fast_rcp(as[kg + 3]); zv.w = z;
            z = (YGET(kg + 2) - bs[kg + 2] * z) * fast_rcp(as[kg + 2]); zv.z = z;
            z = (YGET(kg + 1) - bs[kg + 1] * z) * fast_rcp(as[kg + 1]); zv.y = z;
            z = (YGET(kg)     - bs[kg]     * z) * fast_rcp(as[kg]);     zv.x = z;
            *(float4*)(orow + s + kg) = zv;
        }
    }
}

__attribute__((amdgpu_flat_work_group_size(256, 256), amdgpu_waves_per_eu(4, 4)))
__global__ void TriDiagonalLaplaceSolver_kernel(
    const float* __restrict__ x,
    const float* __restrict__ a,
    const float* __restrict__ b,
    const float* __restrict__ c,
    float* __restrict__ out)
{
    const int chunk = blockIdx.x;                    // 0 .. NN/CHUNK-1
    const int row   = blockIdx.y * 256 + threadIdx.x;
    const int s     = chunk * CHUNK;

    const float* xrow = x   + (size_t)row * NN;
    float*       orow = out + (size_t)row * NN;

    if (chunk == 0) {
        solve_window<true, false>(xrow, a, b, c, orow, 0);
    } else if (chunk == (NN / CHUNK) - 1) {
        solve_window<false, true>(xrow, a, b, c, orow, s);
    } else {
        solve_window<false, false>(xrow, a, b, c, orow, s);
    }
}

extern "C" void kernel_launch(void* const* d_in, const int* in_sizes, int n_in,
                              void* d_out, int out_size, void* d_ws, size_t ws_size,
                              hipStream_t stream) {
    const float* x = (const float*)d_in[0];
    const float* a = (const float*)d_in[1];
    const float* b = (const float*)d_in[2];
    const float* c = (const float*)d_in[3];
    float* out = (float*)d_out;

    dim3 grid(NN / CHUNK, BB / 256);   // 128 chunks x 16 row-groups = 2048 blocks
    dim3 block(256);
    TriDiagonalLaplaceSolver_kernel<<<grid, block, 0, stream>>>(x, a, b, c, out);
}